// Round 3
// baseline (10526.537 us; speedup 1.0000x reference)
//
#include <hip/hip_runtime.h>
#include <cstdint>
#include <cstddef>

// Problem constants (B=8, N=2048, M=256)
#define NB 8
#define NN 2048
#define MM 256

typedef unsigned long long u64;

// monotone float->uint map; canonicalize -0 to +0 so float ties == key ties
__device__ __forceinline__ unsigned mapf(float f) {
  unsigned u = __float_as_uint(f + 0.f);
  return ((int)u >= 0) ? (u ^ 0x80000000u) : ~u;
}
__device__ __forceinline__ u64 shflx_u64(u64 v, int m) {
  unsigned lo = (unsigned)__shfl_xor((int)(unsigned)v, m);
  unsigned hi = (unsigned)__shfl_xor((int)(v >> 32), m);
  return ((u64)hi << 32) | lo;
}
// tiered list length: row t only needs enough entries that P(all used) ~ 0
__device__ __forceinline__ int K_of(int t) {
  return (t < 512) ? 8 : (t < 1024) ? 16 : 64;
}

// ---------------------------------------------------------------------------
// init: seed the tagged h-exchange buffer with (h0, tag=0)
// ---------------------------------------------------------------------------
__global__ void init_k(const float* __restrict__ h0, u64* __restrict__ Hbuf) {
  const int i = threadIdx.x;  // 256
  const u64 pv = (u64)__float_as_uint(h0[i]);
  for (int b = 0; b < NB; ++b)
    __hip_atomic_store(&Hbuf[(b * 2 + 0) * MM + i], pv,
                       __ATOMIC_RELAXED, __HIP_MEMORY_SCOPE_AGENT);
}

// ---------------------------------------------------------------------------
// Phase A: LSTM trajectory + fused Q projection (unchanged from round 2).
// ---------------------------------------------------------------------------
__global__ __launch_bounds__(1024) void lstm_kernel(
    const float* __restrict__ z_g, const float* __restrict__ dec,
    const float* __restrict__ w_ih, const float* __restrict__ w_hh,
    const float* __restrict__ b_ih, const float* __restrict__ b_hh,
    const float* __restrict__ Wq, const float* __restrict__ bq,
    float* __restrict__ Qout, u64* __restrict__ Hbuf)
{
  const int j = blockIdx.x;
  const int b = blockIdx.y;
  const int tid = threadIdx.x;
  const int w = tid >> 6;
  const int lane = tid & 63;
  const int q = w & 7;
  const int rg = w >> 3;
  const int lr = rg * 64 + lane;
  const int g = lr >> 5;
  const int mi = lr & 31;
  const int grow = g * 256 + 32 * j + mi;

  __shared__ __align__(16) float part[128 * 12];
  __shared__ __align__(16) float part2[32 * 36];
  __shared__ __align__(16) float h_s[256];
  __shared__ __align__(16) float xb_s[128];

  float wreg[32];
  {
    const float* wr = w_hh + (size_t)grow * MM + 32 * q;
    #pragma unroll
    for (int i = 0; i < 8; ++i) {
      float4 v = *(const float4*)(wr + 4 * i);
      wreg[4 * i + 0] = v.x; wreg[4 * i + 1] = v.y;
      wreg[4 * i + 2] = v.z; wreg[4 * i + 3] = v.w;
    }
  }
  const int qrow = 32 * j + mi;
  const int qcol = 32 * q + 8 * g;
  float4 wq0, wq1;
  {
    const float* wr = Wq + (size_t)qrow * MM + qcol;
    wq0 = *(const float4*)(wr);
    wq1 = *(const float4*)(wr + 4);
  }

  {
    float p = 0.f;
    const float* wr = w_ih + (size_t)grow * MM + 32 * q;
    #pragma unroll
    for (int i = 0; i < 8; ++i) {
      float4 wv = *(const float4*)(wr + 4 * i);
      float4 dv = *(const float4*)(dec + 32 * q + 4 * i);
      p += wv.x * dv.x + wv.y * dv.y + wv.z * dv.z + wv.w * dv.w;
    }
    part[lr * 12 + q] = p;
  }
  __syncthreads();
  if (w == 0) {
    #pragma unroll
    for (int rr = 0; rr < 2; ++rr) {
      const int lr2 = lane + rr * 64;
      const int g2 = lr2 >> 5, mi2 = lr2 & 31;
      const int grow2 = g2 * 256 + 32 * j + mi2;
      float4 p0 = *(const float4*)&part[lr2 * 12];
      float4 p1 = *(const float4*)&part[lr2 * 12 + 4];
      xb_s[lr2] = p0.x + p0.y + p0.z + p0.w + p1.x + p1.y + p1.z + p1.w
                + b_ih[grow2] + b_hh[grow2];
    }
  }
  float c_my = 0.f;
  if (w == 0 && lane < 32) c_my = z_g[b * MM + 32 * j + lane];
  __syncthreads();

  u64* hb = Hbuf + (size_t)b * 2 * MM;
  const float bqv = (w == 1 && lane < 32) ? bq[32 * j + lane] : 0.f;

  for (int t = 0; t <= NN; ++t) {
    u64* hp = hb + (size_t)((t & 1)) * MM + 32 * q + (lane & 31);
    u64 pv = __hip_atomic_load(hp, __ATOMIC_RELAXED, __HIP_MEMORY_SCOPE_AGENT);
    while (!__all((int)((unsigned)(pv >> 32) == (unsigned)t))) {
      __builtin_amdgcn_s_sleep(1);
      pv = __hip_atomic_load(hp, __ATOMIC_RELAXED, __HIP_MEMORY_SCOPE_AGENT);
    }
    const int hvi = (int)(unsigned)pv;

    float acc = 0.f;
    #pragma unroll
    for (int k = 0; k < 32; ++k) {
      const float hk = __uint_as_float((unsigned)__builtin_amdgcn_readlane(hvi, k));
      acc = fmaf(hk, wreg[k], acc);
    }
    part[lr * 12 + q] = acc;
    if (rg == 0 && lane < 32) h_s[q * 32 + lane] = __uint_as_float((unsigned)pv);
    __syncthreads();

    if (w == 0 && lane < 32 && t < NN) {
      const int m = lane;
      float gate[4];
      #pragma unroll
      for (int gg = 0; gg < 4; ++gg) {
        const int row = gg * 32 + m;
        float4 p0 = *(const float4*)&part[row * 12];
        float4 p1 = *(const float4*)&part[row * 12 + 4];
        gate[gg] = xb_s[row] + p0.x + p0.y + p0.z + p0.w
                             + p1.x + p1.y + p1.z + p1.w;
      }
      const float ig = 1.f / (1.f + __expf(-gate[0]));
      const float fg = 1.f / (1.f + __expf(-gate[1]));
      const float gg_ = 2.f / (1.f + __expf(-2.f * gate[2])) - 1.f;
      const float og = 1.f / (1.f + __expf(-gate[3]));
      c_my = fg * c_my + ig * gg_;
      const float hn = og * (2.f / (1.f + __expf(-2.f * c_my)) - 1.f);
      const u64 pk = ((u64)(unsigned)(t + 1) << 32) | (u64)__float_as_uint(hn);
      __hip_atomic_store(&hb[(size_t)((t + 1) & 1) * MM + 32 * j + m], pk,
                         __ATOMIC_RELAXED, __HIP_MEMORY_SCOPE_AGENT);
    }

    if (t > 0) {
      float4 h0v = *(const float4*)&h_s[qcol];
      float4 h1v = *(const float4*)&h_s[qcol + 4];
      float qa = h0v.x * wq0.x + h0v.y * wq0.y + h0v.z * wq0.z + h0v.w * wq0.w
               + h1v.x * wq1.x + h1v.y * wq1.y + h1v.z * wq1.z + h1v.w * wq1.w;
      part2[mi * 36 + q * 4 + g] = qa;
    }
    __syncthreads();

    if (t > 0 && w == 1 && lane < 32) {
      float s = 0.f;
      #pragma unroll
      for (int c = 0; c < 8; ++c) {
        float4 p = *(const float4*)&part2[lane * 36 + 4 * c];
        s += p.x + p.y + p.z + p.w;
      }
      Qout[((size_t)b * NN + (t - 1)) * MM + 32 * j + lane] = s + bqv;
    }
  }
}

// ---------------------------------------------------------------------------
// C = A @ B^T (+ col bias). 128x128 tile, 256 threads, 8x8 micro-tile
// (unchanged from round 2).
// ---------------------------------------------------------------------------
__global__ __launch_bounds__(256) void gemm128(
    const float* __restrict__ A, const float* __restrict__ B,
    float* __restrict__ C, const float* __restrict__ bias,
    int K, int Ncol, long sA, long sB, long sC)
{
  __shared__ __align__(16) float As[32][132];
  __shared__ __align__(16) float Bs[32][132];
  const int tid = threadIdx.x;
  const int tx = tid & 15;
  const int ty = tid >> 4;
  const int row0 = blockIdx.y * 128;
  const int col0 = blockIdx.x * 128;
  const float* Ab = A + (size_t)blockIdx.z * (size_t)sA;
  const float* Bb = B + (size_t)blockIdx.z * (size_t)sB;
  float* Cb = C + (size_t)blockIdx.z * (size_t)sC;

  float acc[8][8];
  #pragma unroll
  for (int i = 0; i < 8; ++i)
    #pragma unroll
    for (int jj = 0; jj < 8; ++jj) acc[i][jj] = 0.f;

  for (int k0 = 0; k0 < K; k0 += 32) {
    #pragma unroll
    for (int it = 0; it < 4; ++it) {
      const int idx = tid + it * 256;
      const int r = idx >> 3;
      const int c4 = (idx & 7) << 2;
      float4 va = *(const float4*)(Ab + (size_t)(row0 + r) * K + k0 + c4);
      float4 vb = *(const float4*)(Bb + (size_t)(col0 + r) * K + k0 + c4);
      As[c4 + 0][r] = va.x; As[c4 + 1][r] = va.y;
      As[c4 + 2][r] = va.z; As[c4 + 3][r] = va.w;
      Bs[c4 + 0][r] = vb.x; Bs[c4 + 1][r] = vb.y;
      Bs[c4 + 2][r] = vb.z; Bs[c4 + 3][r] = vb.w;
    }
    __syncthreads();
    #pragma unroll
    for (int kk = 0; kk < 32; ++kk) {
      float4 a0 = *(const float4*)&As[kk][ty * 4];
      float4 a1 = *(const float4*)&As[kk][64 + ty * 4];
      float4 b0 = *(const float4*)&Bs[kk][tx * 4];
      float4 b1 = *(const float4*)&Bs[kk][64 + tx * 4];
      const float av[8] = {a0.x, a0.y, a0.z, a0.w, a1.x, a1.y, a1.z, a1.w};
      const float bv[8] = {b0.x, b0.y, b0.z, b0.w, b1.x, b1.y, b1.z, b1.w};
      #pragma unroll
      for (int i = 0; i < 8; ++i)
        #pragma unroll
        for (int jj = 0; jj < 8; ++jj)
          acc[i][jj] = fmaf(av[i], bv[jj], acc[i][jj]);
    }
    __syncthreads();
  }

  #pragma unroll
  for (int i = 0; i < 8; ++i) {
    const int r = row0 + ((i < 4) ? (ty * 4 + i) : (64 + ty * 4 + i - 4));
    float* cp = Cb + (size_t)r * Ncol + col0;
    float4 o0, o1;
    float* o0p = &o0.x; float* o1p = &o1.x;
    #pragma unroll
    for (int jj = 0; jj < 4; ++jj) {
      float v0 = acc[i][jj], v1 = acc[i][jj + 4];
      if (bias) {
        v0 += bias[col0 + tx * 4 + jj];
        v1 += bias[col0 + 64 + tx * 4 + jj];
      }
      o0p[jj] = v0; o1p[jj] = v1;
    }
    *(float4*)(cp + tx * 4) = o0;
    *(float4*)(cp + 64 + tx * 4) = o1;
  }
}

// ---------------------------------------------------------------------------
// Phase D1 (parallel): per-row top-K sorted extraction.
// One wave per row (16384 blocks). Keys packed (value,index) into u64 so max
// == (value desc, index asc). Per-lane cached max + cooperative LDS rescan of
// the winner's 32-element segment (swizzled [i*64 + (lane+i)&63] layout).
// Output: topk[row*64 + r] = r-th best key (r < K_of(t)); 0 elsewhere.
// ---------------------------------------------------------------------------
__global__ __launch_bounds__(64) void topk_kernel(
    const float* __restrict__ S, u64* __restrict__ topk)
{
  const int row = blockIdx.x;           // b*NN + t
  const int t = row & (NN - 1);
  const int lane = threadIdx.x;
  const int rounds = K_of(t);

  __shared__ u64 kl[32 * 64];           // 16 KB

  const float* Sr = S + (size_t)row * NN;
  u64 lmax = 0;
  #pragma unroll
  for (int u = 0; u < 8; ++u) {
    float4 f = *(const float4*)(Sr + u * 256 + lane * 4);
    float fv[4] = {f.x, f.y, f.z, f.w};
    #pragma unroll
    for (int c = 0; c < 4; ++c) {
      const int i = u * 4 + c;
      const int idx = u * 256 + lane * 4 + c;
      const u64 k = ((u64)mapf(fv[c]) << 32) | (unsigned)(NN - 1 - idx);
      kl[i * 64 + ((lane + i) & 63)] = k;
      if (k > lmax) lmax = k;
    }
  }
  __syncthreads();

  u64 kout = 0;
  for (int r = 0; r < rounds; ++r) {
    // global max among per-lane cached maxima
    u64 m = lmax;
    #pragma unroll
    for (int off = 1; off < 64; off <<= 1) {
      u64 o = shflx_u64(m, off);
      if (o > m) m = o;
    }
    if (lane == r) kout = m;
    const u64 bal = __ballot(lmax == m);
    const int wl = (int)__builtin_ctzll(bal);   // winner lane (unique key)
    // cooperative rescan of winner's segment; clear the extracted slot
    const int i = lane & 31;
    const int a = i * 64 + ((wl + i) & 63);
    u64 kk = kl[a];
    if (kk == m) { kl[a] = 0; kk = 0; }
    #pragma unroll
    for (int off = 1; off < 64; off <<= 1) {
      u64 o = shflx_u64(kk, off);
      if (o > kk) kk = o;
    }
    if (lane == wl) lmax = kk;
    __syncthreads();
  }
  topk[(size_t)row * 64 + lane] = kout;
}

// ---------------------------------------------------------------------------
// Phase D2 (sequential, 8 waves): greedy selection chain over top-K lists.
// Used-bitmap distributed across registers (lane w owns idx in [32w,32w+32)).
// Per step: 512B list load (depth-4 prefetch), 1 shuffle bitmap test,
// ballot+ctz -> first unused (= exact masked argmax). Fallback (~31x/batch):
// full-row rescan. Writes sel[idx] = step.
// ---------------------------------------------------------------------------
__global__ __launch_bounds__(64) void select_topk(
    const u64* __restrict__ topk, const float* __restrict__ S,
    int* __restrict__ sel)
{
  const int b = blockIdx.x;
  const int lane = threadIdx.x;
  const u64* tk = topk + (size_t)b * NN * 64 + lane;
  const float* Sb = S + (size_t)b * NN * NN;
  int* selb = sel + b * NN;

  unsigned mybits = 0;   // used flags for idx in [32*lane, 32*lane+32)

  auto step = [&](u64 key, int t) {
    const int idx = (NN - 1) - (int)(key & 0x7ff);
    const unsigned w = (unsigned)__shfl((int)mybits, idx >> 5);
    const bool unused = ((w >> (idx & 31)) & 1u) == 0u;
    const u64 bal = __ballot(unused && (lane < K_of(t)));
    int sidx;
    if (bal != 0) {
      const int l = (int)__builtin_ctzll(bal);
      sidx = __shfl(idx, l);
    } else {
      // fallback: exact masked argmax over the full row
      const float* Sr = Sb + (size_t)t * NN;
      u64 best = 0;
      for (int u = 0; u < 32; ++u) {
        const int ix = 64 * u + lane;
        const float v = Sr[ix];
        const unsigned ww = (unsigned)__shfl((int)mybits, 2 * u + (lane >> 5));
        const bool un = ((ww >> (ix & 31)) & 1u) == 0u;
        const u64 k = ((u64)mapf(v) << 32) | (unsigned)(NN - 1 - ix);
        if (un && k > best) best = k;
      }
      #pragma unroll
      for (int off = 1; off < 64; off <<= 1) {
        u64 o = shflx_u64(best, off);
        if (o > best) best = o;
      }
      sidx = (NN - 1) - (int)(best & 0x7ff);
    }
    if (lane == (sidx >> 5)) mybits |= 1u << (sidx & 31);
    if (lane == 0) selb[sidx] = t;
  };

  u64 k0 = tk[(size_t)0 * 64];
  u64 k1 = tk[(size_t)1 * 64];
  u64 k2 = tk[(size_t)2 * 64];
  u64 k3 = tk[(size_t)3 * 64];
  for (int t = 0; t < NN; t += 4) {
    const int p4 = (t + 4 < NN) ? t + 4 : NN - 1;
    const int p5 = (t + 5 < NN) ? t + 5 : NN - 1;
    const int p6 = (t + 6 < NN) ? t + 6 : NN - 1;
    const int p7 = (t + 7 < NN) ? t + 7 : NN - 1;
    step(k0, t);     k0 = tk[(size_t)p4 * 64];
    step(k1, t + 1); k1 = tk[(size_t)p5 * 64];
    step(k2, t + 2); k2 = tk[(size_t)p6 * 64];
    step(k3, t + 3); k3 = tk[(size_t)p7 * 64];
  }
}

// ---------------------------------------------------------------------------
// Phase E: in-place masked softmax per row (unchanged).
// ---------------------------------------------------------------------------
__global__ __launch_bounds__(256) void softmax_kernel(
    float* __restrict__ out, const int* __restrict__ sel)
{
  const int t = blockIdx.x;
  const int b = blockIdx.y;
  const int tid = threadIdx.x;
  float* row = out + ((size_t)b * NN + t) * NN;
  const int* selb = sel + b * NN;
  __shared__ float red[8];

  float v[8];
  int sl[8];
  #pragma unroll
  for (int u = 0; u < 2; ++u) {
    float4 f = *(const float4*)(row + u * 1024 + tid * 4);
    int4 s4 = *(const int4*)(selb + u * 1024 + tid * 4);
    v[u * 4 + 0] = f.x; v[u * 4 + 1] = f.y; v[u * 4 + 2] = f.z; v[u * 4 + 3] = f.w;
    sl[u * 4 + 0] = s4.x; sl[u * 4 + 1] = s4.y; sl[u * 4 + 2] = s4.z; sl[u * 4 + 3] = s4.w;
  }

  float mx = -3.0e38f;
  #pragma unroll
  for (int e = 0; e < 8; ++e)
    if (sl[e] >= t) mx = fmaxf(mx, v[e]);
  #pragma unroll
  for (int off = 1; off < 64; off <<= 1) mx = fmaxf(mx, __shfl_xor(mx, off));
  if ((tid & 63) == 0) red[tid >> 6] = mx;
  __syncthreads();
  mx = fmaxf(fmaxf(red[0], red[1]), fmaxf(red[2], red[3]));

  float e8[8];
  float sum = 0.f;
  #pragma unroll
  for (int e = 0; e < 8; ++e) {
    float ex = (sl[e] >= t) ? __expf(v[e] - mx) : 0.f;
    e8[e] = ex;
    sum += ex;
  }
  #pragma unroll
  for (int off = 1; off < 64; off <<= 1) sum += __shfl_xor(sum, off);
  if ((tid & 63) == 0) red[4 + (tid >> 6)] = sum;
  __syncthreads();
  sum = red[4] + red[5] + red[6] + red[7];
  const float inv = 1.f / sum;

  #pragma unroll
  for (int u = 0; u < 2; ++u) {
    float4 o;
    o.x = e8[u * 4 + 0] * inv; o.y = e8[u * 4 + 1] * inv;
    o.z = e8[u * 4 + 2] * inv; o.w = e8[u * 4 + 3] * inv;
    *(float4*)(row + u * 1024 + tid * 4) = o;
  }
}

// ---------------------------------------------------------------------------
// ws layout (floats): keys[4194304] | Q[4194304] | Hbuf(u64 4096) | sel[16384]
// topk (8 MB) reuses the keys region (dead after the S gemm). Total ~33.7 MB.
// ---------------------------------------------------------------------------
extern "C" void kernel_launch(void* const* d_in, const int* in_sizes, int n_in,
                              void* d_out, int out_size, void* d_ws, size_t ws_size,
                              hipStream_t stream)
{
  (void)in_sizes; (void)n_in; (void)out_size; (void)ws_size;
  const float* emb  = (const float*)d_in[0];
  const float* z_g  = (const float*)d_in[1];
  const float* dec  = (const float*)d_in[2];
  const float* h0   = (const float*)d_in[3];
  const float* w_ih = (const float*)d_in[4];
  const float* w_hh = (const float*)d_in[5];
  const float* b_ih = (const float*)d_in[6];
  const float* b_hh = (const float*)d_in[7];
  const float* Wq   = (const float*)d_in[8];
  const float* bq   = (const float*)d_in[9];
  const float* Wk   = (const float*)d_in[10];
  const float* bk   = (const float*)d_in[11];
  float* out = (float*)d_out;
  float* ws  = (float*)d_ws;

  float* keys = ws;
  float* Q    = ws + 4194304;
  u64*   Hbuf = (u64*)(ws + 8388608);   // 4096 u64 = 32 KB
  int*   sel  = (int*)(ws + 8396800);
  u64*   topk = (u64*)ws;               // reuses keys region after S gemm

  init_k<<<1, 256, 0, stream>>>(h0, Hbuf);

  lstm_kernel<<<dim3(8, NB), 1024, 0, stream>>>(
      z_g, dec, w_ih, w_hh, b_ih, b_hh, Wq, bq, Q, Hbuf);

  gemm128<<<dim3(MM / 128, (NB * NN) / 128, 1), 256, 0, stream>>>(
      emb, Wk, keys, bk, MM, MM, 0, 0, 0);

  gemm128<<<dim3(NN / 128, NN / 128, NB), 256, 0, stream>>>(
      Q, keys, out, nullptr, MM, NN,
      (long)NN * MM, (long)NN * MM, (long)NN * NN);

  topk_kernel<<<NB * NN, 64, 0, stream>>>(out, topk);

  select_topk<<<NB, 64, 0, stream>>>(topk, out, sel);

  softmax_kernel<<<dim3(NN, NB), 256, 0, stream>>>(out, sel);
}

// Round 4
// 5483.770 us; speedup vs baseline: 1.9196x; 1.9196x over previous
//
#include <hip/hip_runtime.h>
#include <cstdint>
#include <cstddef>

// Problem constants (B=8, N=2048, M=256)
#define NB 8
#define NN 2048
#define MM 256

typedef unsigned long long u64;

// monotone float->uint map; canonicalize -0 to +0 so float ties == key ties
__device__ __forceinline__ unsigned mapf(float f) {
  unsigned u = __float_as_uint(f + 0.f);
  return ((int)u >= 0) ? (u ^ 0x80000000u) : ~u;
}
__device__ __forceinline__ u64 shflx_u64(u64 v, int m) {
  unsigned lo = (unsigned)__shfl_xor((int)(unsigned)v, m);
  unsigned hi = (unsigned)__shfl_xor((int)(v >> 32), m);
  return ((u64)hi << 32) | lo;
}

// ---------------------------------------------------------------------------
// Phase A: LSTM trajectory + fused Q projection.
// grid(8 j-blocks, 8 batches) x 1024 threads (16 waves).
// Block (j,b) owns m in [32j,32j+32) -> 128 gate rows, full k in registers.
// h exchange: producers store tagged u64 (value | (t+1)<<32) to LLC; ONE
// poller wave (w==2) per block polls all 256 entries (4 u64/lane) and
// rebroadcasts h into LDS. All waves matvec from LDS. Two barriers/step.
// Poison-safe without init: tags increase 1..NN; 0xAAAAAAAA never matches
// before the slot's first real store.
// ---------------------------------------------------------------------------
__global__ __launch_bounds__(1024) void lstm_kernel(
    const float* __restrict__ z_g, const float* __restrict__ dec,
    const float* __restrict__ h0, const float* __restrict__ w_ih,
    const float* __restrict__ w_hh, const float* __restrict__ b_ih,
    const float* __restrict__ b_hh, const float* __restrict__ Wq,
    const float* __restrict__ bq, float* __restrict__ Qout,
    u64* __restrict__ Hbuf)
{
  const int j = blockIdx.x;
  const int b = blockIdx.y;
  const int tid = threadIdx.x;
  const int w = tid >> 6;
  const int lane = tid & 63;
  const int q = w & 7;
  const int rg = w >> 3;
  const int lr = rg * 64 + lane;     // 0..127
  const int g = lr >> 5;
  const int mi = lr & 31;
  const int grow = g * 256 + 32 * j + mi;

  __shared__ __align__(16) float part[128 * 12];   // gate partials [lr][q]
  __shared__ __align__(16) float part2[32 * 36];   // q partials [mi][q*4+g]
  __shared__ __align__(16) float h_s[256];
  __shared__ __align__(16) float xb_s[128];

  // recurrent weights -> 32 registers (8 float4, constant-indexed)
  float wreg[32];
  {
    const float* wr = w_hh + (size_t)grow * MM + 32 * q;
    #pragma unroll
    for (int i = 0; i < 8; ++i) {
      float4 v = *(const float4*)(wr + 4 * i);
      wreg[4 * i + 0] = v.x; wreg[4 * i + 1] = v.y;
      wreg[4 * i + 2] = v.z; wreg[4 * i + 3] = v.w;
    }
  }
  // Wq slice: row 32j+mi, cols [32q+8g, 32q+8g+8)
  const int qrow = 32 * j + mi;
  const int qcol = 32 * q + 8 * g;
  float4 wq0, wq1;
  {
    const float* wr = Wq + (size_t)qrow * MM + qcol;
    wq0 = *(const float4*)(wr);
    wq1 = *(const float4*)(wr + 4);
  }

  // xb = dec@w_ih.T + b_ih + b_hh (constant LSTM input)
  {
    float p = 0.f;
    const float* wr = w_ih + (size_t)grow * MM + 32 * q;
    #pragma unroll
    for (int i = 0; i < 8; ++i) {
      float4 wv = *(const float4*)(wr + 4 * i);
      float4 dv = *(const float4*)(dec + 32 * q + 4 * i);
      p += wv.x * dv.x + wv.y * dv.y + wv.z * dv.z + wv.w * dv.w;
    }
    part[lr * 12 + q] = p;
  }
  if (tid < 256) h_s[tid] = h0[tid];   // h^(0)
  __syncthreads();
  if (w == 0) {
    #pragma unroll
    for (int rr = 0; rr < 2; ++rr) {
      const int lr2 = lane + rr * 64;
      const int g2 = lr2 >> 5, mi2 = lr2 & 31;
      const int grow2 = g2 * 256 + 32 * j + mi2;
      float4 p0 = *(const float4*)&part[lr2 * 12];
      float4 p1 = *(const float4*)&part[lr2 * 12 + 4];
      xb_s[lr2] = p0.x + p0.y + p0.z + p0.w + p1.x + p1.y + p1.z + p1.w
                + b_ih[grow2] + b_hh[grow2];
    }
  }
  float c_my = 0.f;
  if (w == 0 && lane < 32) c_my = z_g[b * MM + 32 * j + lane];
  __syncthreads();

  u64* hb = Hbuf + (size_t)b * 2 * MM;
  const float bqv = (w == 1 && lane < 32) ? bq[32 * j + lane] : 0.f;

  for (int t = 0; t <= NN; ++t) {
    // ---- phase 1 (all waves): matvec partials from h_s = h^(t);
    //      plus q-projection partials (also h^(t)) ----
    {
      float acc = 0.f;
      const float* hp = &h_s[32 * q];
      #pragma unroll
      for (int i = 0; i < 8; ++i) {
        float4 hv = *(const float4*)(hp + 4 * i);
        acc = fmaf(hv.x, wreg[4 * i + 0], acc);
        acc = fmaf(hv.y, wreg[4 * i + 1], acc);
        acc = fmaf(hv.z, wreg[4 * i + 2], acc);
        acc = fmaf(hv.w, wreg[4 * i + 3], acc);
      }
      part[lr * 12 + q] = acc;
    }
    if (t > 0) {
      float4 h0v = *(const float4*)&h_s[qcol];
      float4 h1v = *(const float4*)&h_s[qcol + 4];
      float qa = h0v.x * wq0.x + h0v.y * wq0.y + h0v.z * wq0.z + h0v.w * wq0.w
               + h1v.x * wq1.x + h1v.y * wq1.y + h1v.z * wq1.z + h1v.w * wq1.w;
      part2[mi * 36 + q * 4 + g] = qa;
    }
    __syncthreads();   // barrier 1

    // ---- phase 2a: wave 0 = cell update + publish own 32 tagged h ----
    if (t < NN && w == 0 && lane < 32) {
      const int m = lane;
      float gate[4];
      #pragma unroll
      for (int gg = 0; gg < 4; ++gg) {
        const int row = gg * 32 + m;
        float4 p0 = *(const float4*)&part[row * 12];
        float4 p1 = *(const float4*)&part[row * 12 + 4];
        gate[gg] = xb_s[row] + p0.x + p0.y + p0.z + p0.w
                             + p1.x + p1.y + p1.z + p1.w;
      }
      const float ig = 1.f / (1.f + __expf(-gate[0]));
      const float fg = 1.f / (1.f + __expf(-gate[1]));
      const float gg_ = 2.f / (1.f + __expf(-2.f * gate[2])) - 1.f;
      const float og = 1.f / (1.f + __expf(-gate[3]));
      c_my = fg * c_my + ig * gg_;
      const float hn = og * (2.f / (1.f + __expf(-2.f * c_my)) - 1.f);
      const u64 pk = ((u64)(unsigned)(t + 1) << 32) | (u64)__float_as_uint(hn);
      __hip_atomic_store(&hb[(size_t)((t + 1) & 1) * MM + 32 * j + m], pk,
                         __ATOMIC_RELAXED, __HIP_MEMORY_SCOPE_AGENT);
    }

    // ---- phase 2b: poller wave gathers h^(t+1) -> LDS ----
    if (t < NN && w == 2) {
      u64* src = hb + (size_t)((t + 1) & 1) * MM + 4 * lane;
      u64 v0, v1, v2, v3;
      const unsigned tg = (unsigned)(t + 1);
      for (;;) {
        v0 = __hip_atomic_load(src + 0, __ATOMIC_RELAXED, __HIP_MEMORY_SCOPE_AGENT);
        v1 = __hip_atomic_load(src + 1, __ATOMIC_RELAXED, __HIP_MEMORY_SCOPE_AGENT);
        v2 = __hip_atomic_load(src + 2, __ATOMIC_RELAXED, __HIP_MEMORY_SCOPE_AGENT);
        v3 = __hip_atomic_load(src + 3, __ATOMIC_RELAXED, __HIP_MEMORY_SCOPE_AGENT);
        const bool ok = ((unsigned)(v0 >> 32) == tg) & ((unsigned)(v1 >> 32) == tg)
                      & ((unsigned)(v2 >> 32) == tg) & ((unsigned)(v3 >> 32) == tg);
        if (__all((int)ok)) break;
        __builtin_amdgcn_s_sleep(1);
      }
      float4 hv;
      hv.x = __uint_as_float((unsigned)v0);
      hv.y = __uint_as_float((unsigned)v1);
      hv.z = __uint_as_float((unsigned)v2);
      hv.w = __uint_as_float((unsigned)v3);
      *(float4*)&h_s[4 * lane] = hv;
    }

    // ---- phase 2c: wave 1 reduces q partials -> Qout row t-1 ----
    if (t > 0 && w == 1 && lane < 32) {
      float s = 0.f;
      #pragma unroll
      for (int c = 0; c < 8; ++c) {
        float4 p = *(const float4*)&part2[lane * 36 + 4 * c];
        s += p.x + p.y + p.z + p.w;
      }
      Qout[((size_t)b * NN + (t - 1)) * MM + 32 * j + lane] = s + bqv;
    }
    __syncthreads();   // barrier 2: h_s = h^(t+1) visible to all
  }
}

// ---------------------------------------------------------------------------
// C = A @ B^T (+ col bias). 128x128 tile, 256 threads, 8x8 micro-tile.
// ---------------------------------------------------------------------------
__global__ __launch_bounds__(256) void gemm128(
    const float* __restrict__ A, const float* __restrict__ B,
    float* __restrict__ C, const float* __restrict__ bias,
    int K, int Ncol, long sA, long sB, long sC)
{
  __shared__ __align__(16) float As[32][132];
  __shared__ __align__(16) float Bs[32][132];
  const int tid = threadIdx.x;
  const int tx = tid & 15;
  const int ty = tid >> 4;
  const int row0 = blockIdx.y * 128;
  const int col0 = blockIdx.x * 128;
  const float* Ab = A + (size_t)blockIdx.z * (size_t)sA;
  const float* Bb = B + (size_t)blockIdx.z * (size_t)sB;
  float* Cb = C + (size_t)blockIdx.z * (size_t)sC;

  float acc[8][8];
  #pragma unroll
  for (int i = 0; i < 8; ++i)
    #pragma unroll
    for (int jj = 0; jj < 8; ++jj) acc[i][jj] = 0.f;

  for (int k0 = 0; k0 < K; k0 += 32) {
    #pragma unroll
    for (int it = 0; it < 4; ++it) {
      const int idx = tid + it * 256;
      const int r = idx >> 3;
      const int c4 = (idx & 7) << 2;
      float4 va = *(const float4*)(Ab + (size_t)(row0 + r) * K + k0 + c4);
      float4 vb = *(const float4*)(Bb + (size_t)(col0 + r) * K + k0 + c4);
      As[c4 + 0][r] = va.x; As[c4 + 1][r] = va.y;
      As[c4 + 2][r] = va.z; As[c4 + 3][r] = va.w;
      Bs[c4 + 0][r] = vb.x; Bs[c4 + 1][r] = vb.y;
      Bs[c4 + 2][r] = vb.z; Bs[c4 + 3][r] = vb.w;
    }
    __syncthreads();
    #pragma unroll
    for (int kk = 0; kk < 32; ++kk) {
      float4 a0 = *(const float4*)&As[kk][ty * 4];
      float4 a1 = *(const float4*)&As[kk][64 + ty * 4];
      float4 b0 = *(const float4*)&Bs[kk][tx * 4];
      float4 b1 = *(const float4*)&Bs[kk][64 + tx * 4];
      const float av[8] = {a0.x, a0.y, a0.z, a0.w, a1.x, a1.y, a1.z, a1.w};
      const float bv[8] = {b0.x, b0.y, b0.z, b0.w, b1.x, b1.y, b1.z, b1.w};
      #pragma unroll
      for (int i = 0; i < 8; ++i)
        #pragma unroll
        for (int jj = 0; jj < 8; ++jj)
          acc[i][jj] = fmaf(av[i], bv[jj], acc[i][jj]);
    }
    __syncthreads();
  }

  #pragma unroll
  for (int i = 0; i < 8; ++i) {
    const int r = row0 + ((i < 4) ? (ty * 4 + i) : (64 + ty * 4 + i - 4));
    float* cp = Cb + (size_t)r * Ncol + col0;
    float4 o0, o1;
    float* o0p = &o0.x; float* o1p = &o1.x;
    #pragma unroll
    for (int jj = 0; jj < 4; ++jj) {
      float v0 = acc[i][jj], v1 = acc[i][jj + 4];
      if (bias) {
        v0 += bias[col0 + tx * 4 + jj];
        v1 += bias[col0 + 64 + tx * 4 + jj];
      }
      o0p[jj] = v0; o1p[jj] = v1;
    }
    *(float4*)(cp + tx * 4) = o0;
    *(float4*)(cp + 64 + tx * 4) = o1;
  }
}

// ---------------------------------------------------------------------------
// Phase D: exact greedy masked argmax chain, one block (512 thr) per batch.
// Thread owns cols [4*tid, 4*tid+4): one float4 per row (depth-4 prefetch),
// 4 used-bits in a register. Per step: local masked max -> wave butterfly ->
// 8 partials in double-buffered LDS -> ONE barrier -> every wave reduces the
// 8 redundantly -> winner idx; owner sets bit; thread 0 writes sel[idx]=t.
// Data-independent timing; no fallback.
// ---------------------------------------------------------------------------
__global__ __launch_bounds__(512) void select_block(
    const float* __restrict__ S, int* __restrict__ sel)
{
  const int b = blockIdx.x;
  const int tid = threadIdx.x;
  const int w = tid >> 6;          // 0..7
  const int lane = tid & 63;
  const float* Sb = S + (size_t)b * NN * NN + 4 * tid;
  int* selb = sel + b * NN;

  __shared__ u64 partial[2][8];

  for (int i = tid; i < NN; i += 512) selb[i] = 0x7fffffff;
  __syncthreads();

  unsigned mybits = 0;                 // used flags for my 4 columns
  const unsigned base = 2047u - 4u * (unsigned)tid;   // low-bits for col 4*tid

  auto stepf = [&](float4 v, int t) {
    u64 k0 = (mybits & 1u) ? 0 : (((u64)mapf(v.x) << 32) | (base - 0u));
    u64 k1 = (mybits & 2u) ? 0 : (((u64)mapf(v.y) << 32) | (base - 1u));
    u64 k2 = (mybits & 4u) ? 0 : (((u64)mapf(v.z) << 32) | (base - 2u));
    u64 k3 = (mybits & 8u) ? 0 : (((u64)mapf(v.w) << 32) | (base - 3u));
    u64 k = k0 > k1 ? k0 : k1;
    if (k2 > k) k = k2;
    if (k3 > k) k = k3;
    #pragma unroll
    for (int off = 1; off < 64; off <<= 1) {
      u64 o = shflx_u64(k, off);
      if (o > k) k = o;
    }
    if (lane == 0) partial[t & 1][w] = k;
    __syncthreads();
    u64 pk = partial[t & 1][lane & 7];
    #pragma unroll
    for (int off = 1; off < 8; off <<= 1) {
      u64 o = shflx_u64(pk, off);
      if (o > pk) pk = o;
    }
    const int idx = 2047 - (int)(pk & 0x7ff);
    if ((idx >> 2) == tid) mybits |= 1u << (idx & 3);
    if (tid == 0) selb[idx] = t;
  };

  float4 r0 = *(const float4*)(Sb + (size_t)0 * NN);
  float4 r1 = *(const float4*)(Sb + (size_t)1 * NN);
  float4 r2 = *(const float4*)(Sb + (size_t)2 * NN);
  float4 r3 = *(const float4*)(Sb + (size_t)3 * NN);
  for (int t = 0; t < NN; t += 4) {
    const size_t p4 = (size_t)((t + 4 < NN) ? t + 4 : NN - 1) * NN;
    const size_t p5 = (size_t)((t + 5 < NN) ? t + 5 : NN - 1) * NN;
    const size_t p6 = (size_t)((t + 6 < NN) ? t + 6 : NN - 1) * NN;
    const size_t p7 = (size_t)((t + 7 < NN) ? t + 7 : NN - 1) * NN;
    stepf(r0, t);     r0 = *(const float4*)(Sb + p4);
    stepf(r1, t + 1); r1 = *(const float4*)(Sb + p5);
    stepf(r2, t + 2); r2 = *(const float4*)(Sb + p6);
    stepf(r3, t + 3); r3 = *(const float4*)(Sb + p7);
  }
}

// ---------------------------------------------------------------------------
// Phase E: in-place masked softmax per row. Row t masks n iff sel[n] < t.
// ---------------------------------------------------------------------------
__global__ __launch_bounds__(256) void softmax_kernel(
    float* __restrict__ out, const int* __restrict__ sel)
{
  const int t = blockIdx.x;
  const int b = blockIdx.y;
  const int tid = threadIdx.x;
  float* row = out + ((size_t)b * NN + t) * NN;
  const int* selb = sel + b * NN;
  __shared__ float red[8];

  float v[8];
  int sl[8];
  #pragma unroll
  for (int u = 0; u < 2; ++u) {
    float4 f = *(const float4*)(row + u * 1024 + tid * 4);
    int4 s4 = *(const int4*)(selb + u * 1024 + tid * 4);
    v[u * 4 + 0] = f.x; v[u * 4 + 1] = f.y; v[u * 4 + 2] = f.z; v[u * 4 + 3] = f.w;
    sl[u * 4 + 0] = s4.x; sl[u * 4 + 1] = s4.y; sl[u * 4 + 2] = s4.z; sl[u * 4 + 3] = s4.w;
  }

  float mx = -3.0e38f;
  #pragma unroll
  for (int e = 0; e < 8; ++e)
    if (sl[e] >= t) mx = fmaxf(mx, v[e]);
  #pragma unroll
  for (int off = 1; off < 64; off <<= 1) mx = fmaxf(mx, __shfl_xor(mx, off));
  if ((tid & 63) == 0) red[tid >> 6] = mx;
  __syncthreads();
  mx = fmaxf(fmaxf(red[0], red[1]), fmaxf(red[2], red[3]));

  float e8[8];
  float sum = 0.f;
  #pragma unroll
  for (int e = 0; e < 8; ++e) {
    float ex = (sl[e] >= t) ? __expf(v[e] - mx) : 0.f;
    e8[e] = ex;
    sum += ex;
  }
  #pragma unroll
  for (int off = 1; off < 64; off <<= 1) sum += __shfl_xor(sum, off);
  if ((tid & 63) == 0) red[4 + (tid >> 6)] = sum;
  __syncthreads();
  sum = red[4] + red[5] + red[6] + red[7];
  const float inv = 1.f / sum;

  #pragma unroll
  for (int u = 0; u < 2; ++u) {
    float4 o;
    o.x = e8[u * 4 + 0] * inv; o.y = e8[u * 4 + 1] * inv;
    o.z = e8[u * 4 + 2] * inv; o.w = e8[u * 4 + 3] * inv;
    *(float4*)(row + u * 1024 + tid * 4) = o;
  }
}

// ---------------------------------------------------------------------------
// ws layout (floats): keys[4194304] | Q[4194304] | Hbuf(u64 4096) | sel[16384]
// ---------------------------------------------------------------------------
extern "C" void kernel_launch(void* const* d_in, const int* in_sizes, int n_in,
                              void* d_out, int out_size, void* d_ws, size_t ws_size,
                              hipStream_t stream)
{
  (void)in_sizes; (void)n_in; (void)out_size; (void)ws_size;
  const float* emb  = (const float*)d_in[0];
  const float* z_g  = (const float*)d_in[1];
  const float* dec  = (const float*)d_in[2];
  const float* h0   = (const float*)d_in[3];
  const float* w_ih = (const float*)d_in[4];
  const float* w_hh = (const float*)d_in[5];
  const float* b_ih = (const float*)d_in[6];
  const float* b_hh = (const float*)d_in[7];
  const float* Wq   = (const float*)d_in[8];
  const float* bq   = (const float*)d_in[9];
  const float* Wk   = (const float*)d_in[10];
  const float* bk   = (const float*)d_in[11];
  float* out = (float*)d_out;
  float* ws  = (float*)d_ws;

  float* keys = ws;
  float* Q    = ws + 4194304;
  u64*   Hbuf = (u64*)(ws + 8388608);   // 4096 u64 = 32 KB
  int*   sel  = (int*)(ws + 8396800);

  lstm_kernel<<<dim3(8, NB), 1024, 0, stream>>>(
      z_g, dec, h0, w_ih, w_hh, b_ih, b_hh, Wq, bq, Q, Hbuf);

  // keys = emb @ Wk.T + bk  ([16384,256] x [256,256]^T)
  gemm128<<<dim3(MM / 128, (NB * NN) / 128, 1), 256, 0, stream>>>(
      emb, Wk, keys, bk, MM, MM, 0, 0, 0);

  // S[b] = Q[b] @ keys[b].T -> straight into d_out
  gemm128<<<dim3(NN / 128, NN / 128, NB), 256, 0, stream>>>(
      Q, keys, out, nullptr, MM, NN,
      (long)NN * MM, (long)NN * MM, (long)NN * NN);

  select_block<<<NB, 512, 0, stream>>>(out, sel);

  softmax_kernel<<<dim3(NN, NB), 256, 0, stream>>>(out, sel);
}

// Round 5
// 5101.837 us; speedup vs baseline: 2.0633x; 1.0749x over previous
//
#include <hip/hip_runtime.h>
#include <cstdint>
#include <cstddef>

// Problem constants (B=8, N=2048, M=256)
#define NB 8
#define NN 2048
#define MM 256

typedef unsigned long long u64;

// monotone float->uint map; canonicalize -0 to +0 so float ties == key ties
__device__ __forceinline__ unsigned mapf(float f) {
  unsigned u = __float_as_uint(f + 0.f);
  return ((int)u >= 0) ? (u ^ 0x80000000u) : ~u;
}
__device__ __forceinline__ u64 shflx_u64(u64 v, int m) {
  unsigned lo = (unsigned)__shfl_xor((int)(unsigned)v, m);
  unsigned hi = (unsigned)__shfl_xor((int)(v >> 32), m);
  return ((u64)hi << 32) | lo;
}

// L1-bypass load (hits the XCD-local L2): the FAST exchange path.
__device__ __forceinline__ u64 load_sc0(const u64* p) {
  u64 v;
  asm volatile("global_load_dwordx2 %0, %1, off sc0\n\ts_waitcnt vmcnt(0)"
               : "=v"(v) : "v"(p) : "memory");
  return v;
}
// Plain store: write-through L1 into the local L2 (fast path publish).
__device__ __forceinline__ void store_plain(u64* p, u64 v) {
  asm volatile("global_store_dwordx2 %0, %1, off" :: "v"(p), "v"(v) : "memory");
}

// ---------------------------------------------------------------------------
// Phase A: LSTM trajectory + fused Q projection.
// grid(NB, 8) x 1024 thr: flat block id = b + 8*j, so the 8 sibling j-blocks
// of batch b land on ONE XCD under round-robin dispatch (locality heuristic
// only — correctness never depends on it).
// Block (j,b) owns m in [32j,32j+32) -> 128 gate rows; thread holds 32 w_hh
// weights. Exchange: tagged u64 (h | (t+1)<<32) published BOTH as a plain
// store (Hfast: local-L2 path) and an agent atomic (Hslow: LLC ground truth).
// Pollers alternate sc0-load(Hfast) / agent-load(Hslow) until all tags match;
// wrong placement degrades to the LLC path, never hangs or corrupts (tag and
// value travel in one atomic word; 0xAA..A poison never equals a live tag).
// ONE barrier per step; partial buffers double-buffered by t&1.
// ---------------------------------------------------------------------------
__global__ __launch_bounds__(1024) void lstm_kernel(
    const float* __restrict__ z_g, const float* __restrict__ dec,
    const float* __restrict__ h0, const float* __restrict__ w_ih,
    const float* __restrict__ w_hh, const float* __restrict__ b_ih,
    const float* __restrict__ b_hh, const float* __restrict__ Wq,
    const float* __restrict__ bq, float* __restrict__ Qout,
    u64* __restrict__ Hfast, u64* __restrict__ Hslow)
{
  const int b = blockIdx.x;
  const int j = blockIdx.y;
  const int tid = threadIdx.x;
  const int w = tid >> 6;
  const int lane = tid & 63;
  const int q = w & 7;           // k-quarter: cols [32q, 32q+32)
  const int rg = w >> 3;         // row-group
  const int lr = rg * 64 + lane; // 0..127 local gate row
  const int g = lr >> 5;         // gate 0..3 (i,f,g,o)
  const int mi = lr & 31;
  const int grow = g * 256 + 32 * j + mi;

  __shared__ __align__(16) float part[2][128 * 12];   // gate partials [lr][q]
  __shared__ __align__(16) float part2[2][32 * 36];   // q partials [mi][q*4+g]

  // recurrent weights -> 32 registers (8 float4, constant-indexed)
  float wreg[32];
  {
    const float* wr = w_hh + (size_t)grow * MM + 32 * q;
    #pragma unroll
    for (int i = 0; i < 8; ++i) {
      float4 v = *(const float4*)(wr + 4 * i);
      wreg[4 * i + 0] = v.x; wreg[4 * i + 1] = v.y;
      wreg[4 * i + 2] = v.z; wreg[4 * i + 3] = v.w;
    }
  }
  // Wq slice: row 32j+mi, cols [32q+8g, 32q+8g+8)
  float wqa[8];
  {
    const float* wr = Wq + (size_t)(32 * j + mi) * MM + 32 * q + 8 * g;
    float4 w0 = *(const float4*)(wr);
    float4 w1 = *(const float4*)(wr + 4);
    wqa[0] = w0.x; wqa[1] = w0.y; wqa[2] = w0.z; wqa[3] = w0.w;
    wqa[4] = w1.x; wqa[5] = w1.y; wqa[6] = w1.z; wqa[7] = w1.w;
  }
  const float bqv = (w == 1 && lane < 32) ? bq[32 * j + lane] : 0.f;

  // xb = dec@w_ih.T + b_ih + b_hh partials via part[0]
  {
    float p = 0.f;
    const float* wr = w_ih + (size_t)grow * MM + 32 * q;
    #pragma unroll
    for (int i = 0; i < 8; ++i) {
      float4 wv = *(const float4*)(wr + 4 * i);
      float4 dv = *(const float4*)(dec + 32 * q + 4 * i);
      p += wv.x * dv.x + wv.y * dv.y + wv.z * dv.z + wv.w * dv.w;
    }
    part[0][lr * 12 + q] = p;
  }
  __syncthreads();

  // wave 0: xb for its two cell rows (lane, lane+64) -> registers
  float xbA = 0.f, xbB = 0.f, c_my = 0.f;
  if (w == 0) {
    #pragma unroll
    for (int rr = 0; rr < 2; ++rr) {
      const int lr2 = lane + rr * 64;
      const int g2 = lr2 >> 5, mi2 = lr2 & 31;
      const int grow2 = g2 * 256 + 32 * j + mi2;
      float4 p0 = *(const float4*)&part[0][lr2 * 12];
      float4 p1 = *(const float4*)&part[0][lr2 * 12 + 4];
      const float xb = p0.x + p0.y + p0.z + p0.w + p1.x + p1.y + p1.z + p1.w
                     + b_ih[grow2] + b_hh[grow2];
      if (rr == 0) xbA = xb; else xbB = xb;
    }
    if (lane < 32) c_my = z_g[b * MM + 32 * j + lane];
  }
  __syncthreads();

  u64* Hf = Hfast + (size_t)b * 512;
  u64* Hs = Hslow + (size_t)b * 512;
  const int hidx = 32 * q + (lane & 31);

  for (int t = 0; t <= NN; ++t) {
    // ---- acquire h^(t) quarter into registers ----
    int hvi;
    if (t == 0) {
      hvi = __float_as_int(h0[hidx]);
    } else {
      const int off = ((t & 1) << 8) + hidx;
      u64 v = load_sc0(Hf + off);
      bool slow = false;
      for (;;) {
        const bool ok = ((unsigned)(v >> 32) == (unsigned)t);
        if (__all((int)ok)) break;
        slow = !slow;
        if (!ok) {
          v = slow ? __hip_atomic_load(Hs + off, __ATOMIC_RELAXED,
                                       __HIP_MEMORY_SCOPE_AGENT)
                   : load_sc0(Hf + off);
        }
      }
      hvi = (int)(unsigned)v;
    }

    // ---- matvec partial: 4 interleaved fma chains over the quarter ----
    {
      float a0 = 0.f, a1 = 0.f, a2 = 0.f, a3 = 0.f;
      #pragma unroll
      for (int k = 0; k < 32; k += 4) {
        a0 = fmaf(__uint_as_float((unsigned)__builtin_amdgcn_readlane(hvi, k + 0)), wreg[k + 0], a0);
        a1 = fmaf(__uint_as_float((unsigned)__builtin_amdgcn_readlane(hvi, k + 1)), wreg[k + 1], a1);
        a2 = fmaf(__uint_as_float((unsigned)__builtin_amdgcn_readlane(hvi, k + 2)), wreg[k + 2], a2);
        a3 = fmaf(__uint_as_float((unsigned)__builtin_amdgcn_readlane(hvi, k + 3)), wreg[k + 3], a3);
      }
      part[t & 1][lr * 12 + q] = (a0 + a1) + (a2 + a3);
    }

    // ---- q-projection partial from the same quarter (h^(t)) ----
    {
      float qa = 0.f;
      #pragma unroll
      for (int i = 0; i < 8; ++i) {
        const float hh = __uint_as_float((unsigned)__shfl(hvi, 8 * g + i));
        qa = fmaf(hh, wqa[i], qa);
      }
      if (t > 0) part2[t & 1][mi * 36 + q * 4 + g] = qa;
    }
    __syncthreads();   // the ONE barrier per step

    // ---- wave 0: cell update on 64 lanes (2 gate rows each) + publish ----
    if (w == 0 && t < NN) {
      const float* pp = &part[t & 1][0];
      float4 A0 = *(const float4*)(pp + lane * 12);
      float4 A1 = *(const float4*)(pp + lane * 12 + 4);
      float4 B0 = *(const float4*)(pp + (lane + 64) * 12);
      float4 B1 = *(const float4*)(pp + (lane + 64) * 12 + 4);
      const float vA = xbA + A0.x + A0.y + A0.z + A0.w + A1.x + A1.y + A1.z + A1.w;
      const float vB = xbB + B0.x + B0.y + B0.z + B0.w + B1.x + B1.y + B1.z + B1.w;
      // lanes<32: vA=i-gate, vB=g-gate; lanes>=32: vA=f-gate, vB=o-gate
      const float s1 = 1.f / (1.f + __expf(-vA));               // sigmoid
      const float e  = __expf(((lane < 32) ? -2.f : -1.f) * vB);
      const float s2 = (lane < 32) ? (2.f / (1.f + e) - 1.f)    // tanh
                                   : (1.f / (1.f + e));         // sigmoid
      const float fo1 = __shfl_xor(s1, 32);   // f (at lanes<32)
      const float fo2 = __shfl_xor(s2, 32);   // o (at lanes<32)
      if (lane < 32) {
        c_my = fo1 * c_my + s1 * s2;
        const float e2 = __expf(-2.f * c_my);
        const float hn = fo2 * (2.f / (1.f + e2) - 1.f);
        const u64 pk = ((u64)(unsigned)(t + 1) << 32) | (u64)__float_as_uint(hn);
        const int so = (((t + 1) & 1) << 8) + 32 * j + lane;
        store_plain(Hf + so, pk);                                  // local L2
        __hip_atomic_store(Hs + so, pk, __ATOMIC_RELAXED,
                           __HIP_MEMORY_SCOPE_AGENT);              // LLC truth
      }
    }

    // ---- wave 1: reduce q partials -> Qout row t-1 (off critical path) ----
    if (w == 1 && t > 0 && lane < 32) {
      float s = 0.f;
      #pragma unroll
      for (int c = 0; c < 8; ++c) {
        float4 p = *(const float4*)&part2[t & 1][lane * 36 + 4 * c];
        s += p.x + p.y + p.z + p.w;
      }
      Qout[((size_t)b * NN + (t - 1)) * MM + 32 * j + lane] = s + bqv;
    }
  }
}

// ---------------------------------------------------------------------------
// C = A @ B^T (+ col bias). 128x128 tile, 256 threads, 8x8 micro-tile.
// ---------------------------------------------------------------------------
__global__ __launch_bounds__(256) void gemm128(
    const float* __restrict__ A, const float* __restrict__ B,
    float* __restrict__ C, const float* __restrict__ bias,
    int K, int Ncol, long sA, long sB, long sC)
{
  __shared__ __align__(16) float As[32][132];
  __shared__ __align__(16) float Bs[32][132];
  const int tid = threadIdx.x;
  const int tx = tid & 15;
  const int ty = tid >> 4;
  const int row0 = blockIdx.y * 128;
  const int col0 = blockIdx.x * 128;
  const float* Ab = A + (size_t)blockIdx.z * (size_t)sA;
  const float* Bb = B + (size_t)blockIdx.z * (size_t)sB;
  float* Cb = C + (size_t)blockIdx.z * (size_t)sC;

  float acc[8][8];
  #pragma unroll
  for (int i = 0; i < 8; ++i)
    #pragma unroll
    for (int jj = 0; jj < 8; ++jj) acc[i][jj] = 0.f;

  for (int k0 = 0; k0 < K; k0 += 32) {
    #pragma unroll
    for (int it = 0; it < 4; ++it) {
      const int idx = tid + it * 256;
      const int r = idx >> 3;
      const int c4 = (idx & 7) << 2;
      float4 va = *(const float4*)(Ab + (size_t)(row0 + r) * K + k0 + c4);
      float4 vb = *(const float4*)(Bb + (size_t)(col0 + r) * K + k0 + c4);
      As[c4 + 0][r] = va.x; As[c4 + 1][r] = va.y;
      As[c4 + 2][r] = va.z; As[c4 + 3][r] = va.w;
      Bs[c4 + 0][r] = vb.x; Bs[c4 + 1][r] = vb.y;
      Bs[c4 + 2][r] = vb.z; Bs[c4 + 3][r] = vb.w;
    }
    __syncthreads();
    #pragma unroll
    for (int kk = 0; kk < 32; ++kk) {
      float4 a0 = *(const float4*)&As[kk][ty * 4];
      float4 a1 = *(const float4*)&As[kk][64 + ty * 4];
      float4 b0 = *(const float4*)&Bs[kk][tx * 4];
      float4 b1 = *(const float4*)&Bs[kk][64 + tx * 4];
      const float av[8] = {a0.x, a0.y, a0.z, a0.w, a1.x, a1.y, a1.z, a1.w};
      const float bv[8] = {b0.x, b0.y, b0.z, b0.w, b1.x, b1.y, b1.z, b1.w};
      #pragma unroll
      for (int i = 0; i < 8; ++i)
        #pragma unroll
        for (int jj = 0; jj < 8; ++jj)
          acc[i][jj] = fmaf(av[i], bv[jj], acc[i][jj]);
    }
    __syncthreads();
  }

  #pragma unroll
  for (int i = 0; i < 8; ++i) {
    const int r = row0 + ((i < 4) ? (ty * 4 + i) : (64 + ty * 4 + i - 4));
    float* cp = Cb + (size_t)r * Ncol + col0;
    float4 o0, o1;
    float* o0p = &o0.x; float* o1p = &o1.x;
    #pragma unroll
    for (int jj = 0; jj < 4; ++jj) {
      float v0 = acc[i][jj], v1 = acc[i][jj + 4];
      if (bias) {
        v0 += bias[col0 + tx * 4 + jj];
        v1 += bias[col0 + 64 + tx * 4 + jj];
      }
      o0p[jj] = v0; o1p[jj] = v1;
    }
    *(float4*)(cp + tx * 4) = o0;
    *(float4*)(cp + 64 + tx * 4) = o1;
  }
}

// ---------------------------------------------------------------------------
// Phase D: exact greedy masked argmax chain, one block (512 thr) per batch.
// ---------------------------------------------------------------------------
__global__ __launch_bounds__(512) void select_block(
    const float* __restrict__ S, int* __restrict__ sel)
{
  const int b = blockIdx.x;
  const int tid = threadIdx.x;
  const int w = tid >> 6;          // 0..7
  const int lane = tid & 63;
  const float* Sb = S + (size_t)b * NN * NN + 4 * tid;
  int* selb = sel + b * NN;

  __shared__ u64 partial[2][8];

  for (int i = tid; i < NN; i += 512) selb[i] = 0x7fffffff;
  __syncthreads();

  unsigned mybits = 0;                 // used flags for my 4 columns
  const unsigned base = 2047u - 4u * (unsigned)tid;

  auto stepf = [&](float4 v, int t) {
    u64 k0 = (mybits & 1u) ? 0 : (((u64)mapf(v.x) << 32) | (base - 0u));
    u64 k1 = (mybits & 2u) ? 0 : (((u64)mapf(v.y) << 32) | (base - 1u));
    u64 k2 = (mybits & 4u) ? 0 : (((u64)mapf(v.z) << 32) | (base - 2u));
    u64 k3 = (mybits & 8u) ? 0 : (((u64)mapf(v.w) << 32) | (base - 3u));
    u64 k = k0 > k1 ? k0 : k1;
    if (k2 > k) k = k2;
    if (k3 > k) k = k3;
    #pragma unroll
    for (int off = 1; off < 64; off <<= 1) {
      u64 o = shflx_u64(k, off);
      if (o > k) k = o;
    }
    if (lane == 0) partial[t & 1][w] = k;
    __syncthreads();
    u64 pk = partial[t & 1][lane & 7];
    #pragma unroll
    for (int off = 1; off < 8; off <<= 1) {
      u64 o = shflx_u64(pk, off);
      if (o > pk) pk = o;
    }
    const int idx = 2047 - (int)(pk & 0x7ff);
    if ((idx >> 2) == tid) mybits |= 1u << (idx & 3);
    if (tid == 0) selb[idx] = t;
  };

  float4 r0 = *(const float4*)(Sb + (size_t)0 * NN);
  float4 r1 = *(const float4*)(Sb + (size_t)1 * NN);
  float4 r2 = *(const float4*)(Sb + (size_t)2 * NN);
  float4 r3 = *(const float4*)(Sb + (size_t)3 * NN);
  for (int t = 0; t < NN; t += 4) {
    const size_t p4 = (size_t)((t + 4 < NN) ? t + 4 : NN - 1) * NN;
    const size_t p5 = (size_t)((t + 5 < NN) ? t + 5 : NN - 1) * NN;
    const size_t p6 = (size_t)((t + 6 < NN) ? t + 6 : NN - 1) * NN;
    const size_t p7 = (size_t)((t + 7 < NN) ? t + 7 : NN - 1) * NN;
    stepf(r0, t);     r0 = *(const float4*)(Sb + p4);
    stepf(r1, t + 1); r1 = *(const float4*)(Sb + p5);
    stepf(r2, t + 2); r2 = *(const float4*)(Sb + p6);
    stepf(r3, t + 3); r3 = *(const float4*)(Sb + p7);
  }
}

// ---------------------------------------------------------------------------
// Phase E: in-place masked softmax per row. Row t masks n iff sel[n] < t.
// ---------------------------------------------------------------------------
__global__ __launch_bounds__(256) void softmax_kernel(
    float* __restrict__ out, const int* __restrict__ sel)
{
  const int t = blockIdx.x;
  const int b = blockIdx.y;
  const int tid = threadIdx.x;
  float* row = out + ((size_t)b * NN + t) * NN;
  const int* selb = sel + b * NN;
  __shared__ float red[8];

  float v[8];
  int sl[8];
  #pragma unroll
  for (int u = 0; u < 2; ++u) {
    float4 f = *(const float4*)(row + u * 1024 + tid * 4);
    int4 s4 = *(const int4*)(selb + u * 1024 + tid * 4);
    v[u * 4 + 0] = f.x; v[u * 4 + 1] = f.y; v[u * 4 + 2] = f.z; v[u * 4 + 3] = f.w;
    sl[u * 4 + 0] = s4.x; sl[u * 4 + 1] = s4.y; sl[u * 4 + 2] = s4.z; sl[u * 4 + 3] = s4.w;
  }

  float mx = -3.0e38f;
  #pragma unroll
  for (int e = 0; e < 8; ++e)
    if (sl[e] >= t) mx = fmaxf(mx, v[e]);
  #pragma unroll
  for (int off = 1; off < 64; off <<= 1) mx = fmaxf(mx, __shfl_xor(mx, off));
  if ((tid & 63) == 0) red[tid >> 6] = mx;
  __syncthreads();
  mx = fmaxf(fmaxf(red[0], red[1]), fmaxf(red[2], red[3]));

  float e8[8];
  float sum = 0.f;
  #pragma unroll
  for (int e = 0; e < 8; ++e) {
    float ex = (sl[e] >= t) ? __expf(v[e] - mx) : 0.f;
    e8[e] = ex;
    sum += ex;
  }
  #pragma unroll
  for (int off = 1; off < 64; off <<= 1) sum += __shfl_xor(sum, off);
  if ((tid & 63) == 0) red[4 + (tid >> 6)] = sum;
  __syncthreads();
  sum = red[4] + red[5] + red[6] + red[7];
  const float inv = 1.f / sum;

  #pragma unroll
  for (int u = 0; u < 2; ++u) {
    float4 o;
    o.x = e8[u * 4 + 0] * inv; o.y = e8[u * 4 + 1] * inv;
    o.z = e8[u * 4 + 2] * inv; o.w = e8[u * 4 + 3] * inv;
    *(float4*)(row + u * 1024 + tid * 4) = o;
  }
}

// ---------------------------------------------------------------------------
// ws layout (floats): keys[4194304] | Q[4194304] | Hfast(u64 4096) |
//                     Hslow(u64 4096) | sel[16384]   ~ 33.7 MB
// ---------------------------------------------------------------------------
extern "C" void kernel_launch(void* const* d_in, const int* in_sizes, int n_in,
                              void* d_out, int out_size, void* d_ws, size_t ws_size,
                              hipStream_t stream)
{
  (void)in_sizes; (void)n_in; (void)out_size; (void)ws_size;
  const float* emb  = (const float*)d_in[0];
  const float* z_g  = (const float*)d_in[1];
  const float* dec  = (const float*)d_in[2];
  const float* h0   = (const float*)d_in[3];
  const float* w_ih = (const float*)d_in[4];
  const float* w_hh = (const float*)d_in[5];
  const float* b_ih = (const float*)d_in[6];
  const float* b_hh = (const float*)d_in[7];
  const float* Wq   = (const float*)d_in[8];
  const float* bq   = (const float*)d_in[9];
  const float* Wk   = (const float*)d_in[10];
  const float* bk   = (const float*)d_in[11];
  float* out = (float*)d_out;
  float* ws  = (float*)d_ws;

  float* keys  = ws;
  float* Q     = ws + 4194304;
  u64*   Hfast = (u64*)(ws + 8388608);
  u64*   Hslow = (u64*)(ws + 8396800);
  int*   sel   = (int*)(ws + 8404992);

  lstm_kernel<<<dim3(NB, 8), 1024, 0, stream>>>(
      z_g, dec, h0, w_ih, w_hh, b_ih, b_hh, Wq, bq, Q, Hfast, Hslow);

  // keys = emb @ Wk.T + bk  ([16384,256] x [256,256]^T)
  gemm128<<<dim3(MM / 128, (NB * NN) / 128, 1), 256, 0, stream>>>(
      emb, Wk, keys, bk, MM, MM, 0, 0, 0);

  // S[b] = Q[b] @ keys[b].T -> straight into d_out
  gemm128<<<dim3(NN / 128, NN / 128, NB), 256, 0, stream>>>(
      Q, keys, out, nullptr, MM, NN,
      (long)NN * MM, (long)NN * MM, (long)NN * NN);

  select_block<<<NB, 512, 0, stream>>>(out, sel);

  softmax_kernel<<<dim3(NN, NB), 256, 0, stream>>>(out, sel);
}